// Round 3
// baseline (202.730 us; speedup 1.0000x reference)
//
#include <hip/hip_runtime.h>
#include <stdint.h>
#include <math.h>

// BSRBF-KAN layer, FUSED + PIPELINED, all-f16 datapath:
// out = relu(LN(x)) @ base_W^T + (bspline+rbf)(LN(x)) @ spline_W^T
// K = 512 (relu region, A0 staged via global_load_lds)
//   + 4096 (basis region, computed per K-tile directly into LDS).
// Round-3 changes vs round-2:
//  * f16 everywhere (W, A0, basis, MFMA f32_16x16x32_f16) - no bf16 repack.
//  * spline selection via 14-entry LDS LUT of v_perm_b32 selectors:
//    v0..v3 packed f16 in 2 regs; per output pair: 1 perm + 1 v_pk_add_f16.
//    (~58 VALU/eval vs ~95.)
//  * counted-vmcnt barriers: raw s_barrier + s_waitcnt vmcnt(6) steady-state;
//    B triple-buffered, GLL(t+2) stays in flight across the barrier.
//  * s_setprio(1) around MFMA cluster (T5).
// Tile: BM=128 x BN=256, BK=64, 8 waves, 128.2 KB LDS, grid=256 (1 block/CU).
//   ws: [W: 512*4608 f16][XN: 16384*512 f16][A0: 16384*512 f16]

#define D_IN  512
#define D_OUT 512
#define NB    8
#define KTOT  (D_IN + D_IN * NB)   // 4608
#define ROWS  16384
#define NT    (KTOT / 64)          // 72

typedef __attribute__((ext_vector_type(2))) _Float16 f16x2;
typedef __attribute__((ext_vector_type(8))) _Float16 f16x8;
typedef __attribute__((ext_vector_type(4))) float f32x4;

__device__ __forceinline__ float h2f(unsigned short u) {
  return (float)__builtin_bit_cast(_Float16, u);
}
__device__ __forceinline__ short f2h(float f) {
  return (short)__builtin_bit_cast(unsigned short, (_Float16)f);  // RNE
}
__device__ __forceinline__ unsigned pkrtz_u(float a, float b) {
  return __builtin_bit_cast(unsigned, __builtin_amdgcn_cvt_pkrtz(a, b));
}
__device__ __forceinline__ unsigned pkadd_f16(unsigned a, unsigned b) {
  f16x2 x = __builtin_bit_cast(f16x2, a), y = __builtin_bit_cast(f16x2, b);
  f16x2 r = x + y;
  return __builtin_bit_cast(unsigned, r);
}

// ---------------- prep: weight interleave + LayerNorm, one launch --------
__global__ __launch_bounds__(256) void prep_kernel(
    const float* __restrict__ x, const float* __restrict__ gamma,
    const float* __restrict__ beta, const float* __restrict__ bw,
    const float* __restrict__ sw, short* __restrict__ XN,
    short* __restrict__ A0, short* __restrict__ W) {
  if (blockIdx.x >= ROWS / 4) {
    const int o = blockIdx.x - ROWS / 4;
    for (int k = threadIdx.x; k < KTOT; k += 256) {
      const float v = (k < D_IN) ? bw[o * D_IN + k]
                                 : sw[(size_t)o * (D_IN * NB) + (k - D_IN)];
      W[(size_t)o * KTOT + k] = f2h(v);
    }
    return;
  }
  const int tid = threadIdx.x;
  const int lane = tid & 63, wave = tid >> 6;
  const int row = blockIdx.x * 4 + wave;
  const float* xr = x + (size_t)row * D_IN + lane * 8;

  const float4 a = *(const float4*)(xr);
  const float4 b = *(const float4*)(xr + 4);
  float xv[8] = {a.x, a.y, a.z, a.w, b.x, b.y, b.z, b.w};
  float s = 0.0f, ss = 0.0f;
#pragma unroll
  for (int e = 0; e < 8; e++) { s += xv[e]; ss += xv[e] * xv[e]; }
#pragma unroll
  for (int off = 32; off > 0; off >>= 1) {
    s += __shfl_xor(s, off);
    ss += __shfl_xor(ss, off);
  }
  const float mu = s * (1.0f / D_IN);
  const float var = ss * (1.0f / D_IN) - mu * mu;
  const float rstd = 1.0f / sqrtf(var + 1e-5f);

  const float4 g0 = *(const float4*)(gamma + lane * 8);
  const float4 g1 = *(const float4*)(gamma + lane * 8 + 4);
  const float4 b0 = *(const float4*)(beta + lane * 8);
  const float4 b1 = *(const float4*)(beta + lane * 8 + 4);
  float gv[8] = {g0.x, g0.y, g0.z, g0.w, g1.x, g1.y, g1.z, g1.w};
  float bv[8] = {b0.x, b0.y, b0.z, b0.w, b1.x, b1.y, b1.z, b1.w};

  unsigned xp[4], rp[4];
#pragma unroll
  for (int h = 0; h < 4; h++) {
    const float n0 = (xv[2 * h] - mu) * rstd * gv[2 * h] + bv[2 * h];
    const float n1 = (xv[2 * h + 1] - mu) * rstd * gv[2 * h + 1] + bv[2 * h + 1];
    const unsigned h0 = (unsigned)(unsigned short)f2h(n0);
    const unsigned h1 = (unsigned)(unsigned short)f2h(n1);
    xp[h] = h0 | (h1 << 16);
    rp[h] = (unsigned)(unsigned short)f2h(fmaxf(n0, 0.0f)) |
            ((unsigned)(unsigned short)f2h(fmaxf(n1, 0.0f)) << 16);
  }
  const uint4 xq = {xp[0], xp[1], xp[2], xp[3]};
  const uint4 rq = {rp[0], rp[1], rp[2], rp[3]};
  *(uint4*)&XN[(size_t)row * D_IN + lane * 8] = xq;
  *(uint4*)&A0[(size_t)row * D_IN + lane * 8] = rq;
}

// ---------------- basis eval: one d -> 8 packed f16 (spline + rbf) -------
// Spline: closed-form uniform cubic, knots (i-3)*0.6 - 1.5; j=c..c-3 get
// v0..v3, rest 0.  Selection: v0..v3 packed f16 in {va,vb}; LUT[c+1] holds 4
// v_perm selectors (byte 2k,2k+1 = v_k; 0x0C = 0x00).
// RBF cascade: z = (xn+1.5)*(7/3)*sqrt(log2 e); R_j = exp2(-(z-j*DLT)^2),
// DLT^2 = log2 e  =>  R_{j+1} = R_j * G * e^-(2j+1), G = exp2(2*DLT*z).
// z clamped to [-8,16]: outside, all R_j < 2^-57 ~ 0 and no inf*0.
__device__ __forceinline__ void basis_write(float xn, const uint4* lut,
                                            short* dst) {
  const float u = fmaf(xn, 1.66666667f, 5.5f);  // (xn+3.3)/0.6
  const float cf = floorf(u);
  const int c = (int)cf;
  const float t = u - cf;
  const float t2 = t * t, t3 = t2 * t, omt = 1.0f - t;
  const float v0 = t3 * 0.16666667f;
  const float v1 = fmaf(fmaf(fmaf(t, -0.5f, 0.5f), t, 0.5f), t, 0.16666667f);
  const float v2 = fmaf(t3, 0.5f, fmaf(t2, -1.0f, 0.66666667f));
  const float v3 = omt * omt * (omt * 0.16666667f);
  const unsigned va = pkrtz_u(v0, v1);
  const unsigned vb = pkrtz_u(v2, v3);

  float z = fmaf(xn, 2.80261895f, 4.20392842f);
  z = fminf(fmaxf(z, -8.0f), 16.0f);
  const float d3 = z - 3.60336723f;              // 3*DLT
  const float R3 = __builtin_amdgcn_exp2f(-(d3 * d3));
  const float G  = __builtin_amdgcn_exp2f(z * 2.40224482f);  // 2*DLT
  const float Gi = __builtin_amdgcn_rcpf(G);
  const float R4 = R3 * (G * 9.11881966e-4f);    // e^-7
  const float R5 = R4 * (G * 1.23409804e-4f);    // e^-9
  const float R6 = R5 * (G * 1.67017007e-5f);    // e^-11
  const float R7 = R6 * (G * 2.26032941e-6f);    // e^-13
  const float R2 = R3 * (Gi * 148.413159f);      // e^5
  const float R1 = R2 * (Gi * 20.0855369f);      // e^3
  const float R0 = R1 * (Gi * 2.71828183f);      // e^1

  const int idx = (c < -1 ? -1 : (c > 12 ? 12 : c)) + 1;
  const uint4 sel = lut[idx];
  const unsigned w0 = pkadd_f16(__builtin_amdgcn_perm(vb, va, sel.x), pkrtz_u(R0, R1));
  const unsigned w1 = pkadd_f16(__builtin_amdgcn_perm(vb, va, sel.y), pkrtz_u(R2, R3));
  const unsigned w2 = pkadd_f16(__builtin_amdgcn_perm(vb, va, sel.z), pkrtz_u(R4, R5));
  const unsigned w3 = pkadd_f16(__builtin_amdgcn_perm(vb, va, sel.w), pkrtz_u(R6, R7));
  const uint4 v4 = {w0, w1, w2, w3};
  *(uint4*)dst = v4;  // ds_write_b128
}

// ---------------- fused pipelined f16 MFMA GEMM --------------------------
// LDS slot (r, c) holds global chunk c ^ (r & 7)  (XOR bank swizzle)
#define GLL(g, l)                                               \
  __builtin_amdgcn_global_load_lds(                             \
      (const __attribute__((address_space(1))) void*)(g),       \
      (__attribute__((address_space(3))) void*)(l), 16, 0, 0)

__global__ __launch_bounds__(512, 2) void gemm_kernel(
    const short* __restrict__ A0, const short* __restrict__ XN,
    const short* __restrict__ W, float* __restrict__ out) {
  __shared__ short As[2 * 128 * 64];  // 32 KB, A double-buffer
  __shared__ short Bs[3 * 256 * 64];  // 96 KB, B triple-buffer (depth-2 GLL)
  __shared__ uint4 LUT[14];
  const int tid = threadIdx.x;
  const int lane = tid & 63, wave = tid >> 6;

  // perm-selector LUT: entry idx = c+1, c clamped to [-1,12]
  if (tid < 14) {
    const int cc = tid - 1;
    unsigned e[4];
#pragma unroll
    for (int h = 0; h < 4; ++h) {
      const int m = cc - 2 * h, m2 = m - 1;
      const unsigned lo =
          (m >= 0 && m <= 3) ? (unsigned)((2 * m) | ((2 * m + 1) << 8)) : 0x0C0Cu;
      const unsigned hi =
          (m2 >= 0 && m2 <= 3) ? (unsigned)((2 * m2) | ((2 * m2 + 1) << 8)) : 0x0C0Cu;
      e[h] = lo | (hi << 16);
    }
    const uint4 ev = {e[0], e[1], e[2], e[3]};
    LUT[tid] = ev;
  }

  const int f = blockIdx.x;          // pair 2g,2g+1 shares one A m-tile
  const int m0 = (f >> 1) * 128;
  const int n0 = (f & 1) * 256;
  const int wm = wave & 1, wn = wave >> 1;  // per-wave 64x64 output

  const f32x4 zero = {0.0f, 0.0f, 0.0f, 0.0f};
  f32x4 acc[4][4];
#pragma unroll
  for (int i = 0; i < 4; i++)
#pragma unroll
    for (int j = 0; j < 4; j++) acc[i][j] = zero;

  // staging map: thread -> (row r0 = tid>>3 in 0..63, chunk-slot c0 = tid&7)
  const int r0 = tid >> 3;
  const int c0 = tid & 7;
  const int q0 = c0 ^ (r0 & 7);
  const short* gA = A0 + (size_t)(m0 + r0) * D_IN + q0 * 8;
  const short* gB = W + (size_t)(n0 + r0) * KTOT + q0 * 8;
  const unsigned short* gXa =
      (const unsigned short*)XN + (size_t)(m0 + r0) * D_IN + q0;
  const unsigned short* gXb = gXa + (size_t)64 * D_IN;

  short* Acur = As;        short* Anxt = As + 128 * 64;
  short* Bcur = Bs;        short* Bnxt = Bs + 256 * 64;  short* Bstg = Bs + 2 * 256 * 64;

  const int lr = lane & 15;
  const int q = lane >> 4;
  const int x7 = lr & 7;

  // prologue: A(0), B(0), B(1).  Need A(0)+B(0) done -> vmcnt(4) leaves B(1).
  GLL(gA, Acur + wave * 512);
  GLL(gA + (size_t)64 * D_IN, Acur + 4096 + wave * 512);
#pragma unroll
  for (int rd = 0; rd < 4; rd++)
    GLL(gB + (size_t)(64 * rd) * KTOT, Bcur + wave * 512 + rd * 4096);
#pragma unroll
  for (int rd = 0; rd < 4; rd++)
    GLL(gB + (size_t)(64 * rd) * KTOT + 64, Bnxt + wave * 512 + rd * 4096);
  asm volatile("s_waitcnt vmcnt(4) lgkmcnt(0)" ::: "memory");
  __builtin_amdgcn_s_barrier();
  __builtin_amdgcn_sched_barrier(0);

  unsigned short ca = 0, cb = 0;   // xn inputs for tile t+1 basis staging
  unsigned short pa = 0, pb = 0;   // xn inputs for tile t+2 (loaded this iter)

  for (int t = 0; t < NT; ++t) {
    // 1. fragments of current tile -> registers
    f16x8 af[2][4], bfv[2][4];
#pragma unroll
    for (int kk2 = 0; kk2 < 2; kk2++) {
      const int off = ((kk2 * 4 + q) ^ x7) * 8;
#pragma unroll
      for (int mi = 0; mi < 4; mi++)
        af[kk2][mi] = *(const f16x8*)&Acur[(wm * 64 + mi * 16 + lr) * 64 + off];
#pragma unroll
      for (int nj = 0; nj < 4; nj++)
        bfv[kk2][nj] = *(const f16x8*)&Bcur[(wn * 64 + nj * 16 + lr) * 64 + off];
    }

    // 2. staging: A(t+1) into Anxt; B(t+2) into Bstg; xn(t+2) prefetch
    const int tp1 = t + 1, tp2 = t + 2;
    if (tp1 < NT && tp1 < 8) {  // relu region: A via GLL
      GLL(gA + tp1 * 64, Anxt + wave * 512);
      GLL(gA + (size_t)64 * D_IN + tp1 * 64, Anxt + 4096 + wave * 512);
    }
    if (tp2 < NT) {
      if (tp2 >= 8) {  // xn prefetch for tile t+2 basis (consumed next iter)
        const int dof = tp2 * 8 - 64;
        pa = gXa[dof];
        pb = gXb[dof];
      }
#pragma unroll
      for (int rd = 0; rd < 4; rd++)
        GLL(gB + (size_t)(64 * rd) * KTOT + tp2 * 64,
            Bstg + wave * 512 + rd * 4096);
    }
    if (tp1 < NT && tp1 >= 8) {  // basis region: compute A(t+1) in-register
      basis_write(h2f(ca), LUT, Anxt + r0 * 64 + c0 * 8);
      basis_write(h2f(cb), LUT, Anxt + (r0 + 64) * 64 + c0 * 8);
    }

    // 3. MFMA on current tile
    __builtin_amdgcn_s_setprio(1);
#pragma unroll
    for (int kk2 = 0; kk2 < 2; kk2++)
#pragma unroll
      for (int mi = 0; mi < 4; mi++)
#pragma unroll
        for (int nj = 0; nj < 4; nj++)
          acc[mi][nj] = __builtin_amdgcn_mfma_f32_16x16x32_f16(
              af[kk2][mi], bfv[kk2][nj], acc[mi][nj], 0, 0, 0);
    __builtin_amdgcn_s_setprio(0);

    // 4. barrier.  Steady state (7 <= t < NT-2): this-iter VMEM = 2 xn + 4
    // B-GLL(t+2) = 6; everything needed (B(t+1) GLLs, basis ds_write) is
    // older -> vmcnt(6) lgkmcnt(0) exact.  Relu region / tail: full drain.
    if (t < NT - 1) {
      if (t >= 7 && t < NT - 2) {
        asm volatile("s_waitcnt vmcnt(6) lgkmcnt(0)" ::: "memory");
      } else {
        asm volatile("s_waitcnt vmcnt(0) lgkmcnt(0)" ::: "memory");
      }
      __builtin_amdgcn_s_barrier();
      __builtin_amdgcn_sched_barrier(0);
    }

    // 5. rotate buffers / shift xn pipeline
    short* tA = Acur; Acur = Anxt; Anxt = tA;
    short* tB = Bcur; Bcur = Bnxt; Bnxt = Bstg; Bstg = tB;
    ca = pa; cb = pb;
  }

  // C/D layout (m89-verified): col = lane&15, row = (lane>>4)*4 + reg
#pragma unroll
  for (int mi = 0; mi < 4; mi++) {
#pragma unroll
    for (int nj = 0; nj < 4; nj++) {
      const int gcol = n0 + wn * 64 + nj * 16 + lr;
#pragma unroll
      for (int r = 0; r < 4; r++) {
        const int grow = m0 + wm * 64 + mi * 16 + q * 4 + r;
        out[(size_t)grow * D_OUT + gcol] = acc[mi][nj][r];
      }
    }
  }
}

extern "C" void kernel_launch(void* const* d_in, const int* in_sizes, int n_in,
                              void* d_out, int out_size, void* d_ws, size_t ws_size,
                              hipStream_t stream) {
  const float* x     = (const float*)d_in[0];
  const float* gamma = (const float*)d_in[1];
  const float* beta  = (const float*)d_in[2];
  const float* bw    = (const float*)d_in[3];
  const float* sw    = (const float*)d_in[4];
  float* out = (float*)d_out;

  short* W  = (short*)d_ws;                          // 512 * 4608 f16
  short* XN = W + (size_t)D_OUT * KTOT;              // 16384 * 512 f16
  short* A0 = XN + (size_t)ROWS * D_IN;              // 16384 * 512 f16

  prep_kernel<<<ROWS / 4 + D_OUT, 256, 0, stream>>>(x, gamma, beta, bw, sw,
                                                    XN, A0, W);
  gemm_kernel<<<256, 512, 0, stream>>>(A0, XN, W, out);
}

// Round 4
// 198.318 us; speedup vs baseline: 1.0222x; 1.0222x over previous
//
#include <hip/hip_runtime.h>
#include <stdint.h>
#include <math.h>

// BSRBF-KAN layer, FUSED + PHASE-SPLIT PIPELINE (round 4):
// out = relu(LN(x)) @ base_W^T + (bspline+rbf)(LN(x)) @ spline_W^T
// K = 512 (relu region, A0 via global_load_lds) + 4096 (basis, computed into LDS).
// Round-4 change vs round-3: same memory map / eval / triple-buffered B /
// counted vmcnt, but the K-loop is split into 2 sub-phases with ONE barrier
// per tile and frag reads placed on the OPPOSITE side of the barrier from
// their consuming MFMA cluster:
//   phase1: read kk2=1 frags(t) || stage A(t+1),B(t+2),xn(t+2) -> MFMA kk2=0
//           (frags read last phase) -> vmcnt(K) lgkmcnt(0) -> barrier
//   phase2: read kk2=0 frags(t+1) -> MFMA kk2=1
// Every MFMA cluster has operands pre-loaded; each 8-read group is
// independent of the adjacent 16-MFMA cluster -> LDS port overlaps matrix
// pipe (round-3 convoy: all-reads-then-all-MFMA, MfmaUtil 27 + VALU 35).
// Tile: BM=128 x BN=256, BK=64, 8 waves, 128.2 KB LDS, grid=256 (1 block/CU).
//   ws: [W: 512*4608 f16][XN: 16384*512 f16][A0: 16384*512 f16]

#define D_IN  512
#define D_OUT 512
#define NB    8
#define KTOT  (D_IN + D_IN * NB)   // 4608
#define ROWS  16384
#define NT    (KTOT / 64)          // 72

typedef __attribute__((ext_vector_type(2))) _Float16 f16x2;
typedef __attribute__((ext_vector_type(8))) _Float16 f16x8;
typedef __attribute__((ext_vector_type(4))) float f32x4;

__device__ __forceinline__ float h2f(unsigned short u) {
  return (float)__builtin_bit_cast(_Float16, u);
}
__device__ __forceinline__ short f2h(float f) {
  return (short)__builtin_bit_cast(unsigned short, (_Float16)f);  // RNE
}
__device__ __forceinline__ unsigned pkrtz_u(float a, float b) {
  return __builtin_bit_cast(unsigned, __builtin_amdgcn_cvt_pkrtz(a, b));
}
__device__ __forceinline__ unsigned pkadd_f16(unsigned a, unsigned b) {
  f16x2 x = __builtin_bit_cast(f16x2, a), y = __builtin_bit_cast(f16x2, b);
  f16x2 r = x + y;
  return __builtin_bit_cast(unsigned, r);
}

// ---------------- prep: weight interleave + LayerNorm, one launch --------
__global__ __launch_bounds__(256) void prep_kernel(
    const float* __restrict__ x, const float* __restrict__ gamma,
    const float* __restrict__ beta, const float* __restrict__ bw,
    const float* __restrict__ sw, short* __restrict__ XN,
    short* __restrict__ A0, short* __restrict__ W) {
  if (blockIdx.x >= ROWS / 4) {
    const int o = blockIdx.x - ROWS / 4;
    for (int k = threadIdx.x; k < KTOT; k += 256) {
      const float v = (k < D_IN) ? bw[o * D_IN + k]
                                 : sw[(size_t)o * (D_IN * NB) + (k - D_IN)];
      W[(size_t)o * KTOT + k] = f2h(v);
    }
    return;
  }
  const int tid = threadIdx.x;
  const int lane = tid & 63, wave = tid >> 6;
  const int row = blockIdx.x * 4 + wave;
  const float* xr = x + (size_t)row * D_IN + lane * 8;

  const float4 a = *(const float4*)(xr);
  const float4 b = *(const float4*)(xr + 4);
  float xv[8] = {a.x, a.y, a.z, a.w, b.x, b.y, b.z, b.w};
  float s = 0.0f, ss = 0.0f;
#pragma unroll
  for (int e = 0; e < 8; e++) { s += xv[e]; ss += xv[e] * xv[e]; }
#pragma unroll
  for (int off = 32; off > 0; off >>= 1) {
    s += __shfl_xor(s, off);
    ss += __shfl_xor(ss, off);
  }
  const float mu = s * (1.0f / D_IN);
  const float var = ss * (1.0f / D_IN) - mu * mu;
  const float rstd = 1.0f / sqrtf(var + 1e-5f);

  const float4 g0 = *(const float4*)(gamma + lane * 8);
  const float4 g1 = *(const float4*)(gamma + lane * 8 + 4);
  const float4 b0 = *(const float4*)(beta + lane * 8);
  const float4 b1 = *(const float4*)(beta + lane * 8 + 4);
  float gv[8] = {g0.x, g0.y, g0.z, g0.w, g1.x, g1.y, g1.z, g1.w};
  float bv[8] = {b0.x, b0.y, b0.z, b0.w, b1.x, b1.y, b1.z, b1.w};

  unsigned xp[4], rp[4];
#pragma unroll
  for (int h = 0; h < 4; h++) {
    const float n0 = (xv[2 * h] - mu) * rstd * gv[2 * h] + bv[2 * h];
    const float n1 = (xv[2 * h + 1] - mu) * rstd * gv[2 * h + 1] + bv[2 * h + 1];
    const unsigned h0 = (unsigned)(unsigned short)f2h(n0);
    const unsigned h1 = (unsigned)(unsigned short)f2h(n1);
    xp[h] = h0 | (h1 << 16);
    rp[h] = (unsigned)(unsigned short)f2h(fmaxf(n0, 0.0f)) |
            ((unsigned)(unsigned short)f2h(fmaxf(n1, 0.0f)) << 16);
  }
  const uint4 xq = {xp[0], xp[1], xp[2], xp[3]};
  const uint4 rq = {rp[0], rp[1], rp[2], rp[3]};
  *(uint4*)&XN[(size_t)row * D_IN + lane * 8] = xq;
  *(uint4*)&A0[(size_t)row * D_IN + lane * 8] = rq;
}

// ---------------- basis eval: one d -> 8 packed f16 (spline + rbf) -------
// (unchanged from round 3, verified)
__device__ __forceinline__ void basis_write(float xn, const uint4* lut,
                                            short* dst) {
  const float u = fmaf(xn, 1.66666667f, 5.5f);  // (xn+3.3)/0.6
  const float cf = floorf(u);
  const int c = (int)cf;
  const float t = u - cf;
  const float t2 = t * t, t3 = t2 * t, omt = 1.0f - t;
  const float v0 = t3 * 0.16666667f;
  const float v1 = fmaf(fmaf(fmaf(t, -0.5f, 0.5f), t, 0.5f), t, 0.16666667f);
  const float v2 = fmaf(t3, 0.5f, fmaf(t2, -1.0f, 0.66666667f));
  const float v3 = omt * omt * (omt * 0.16666667f);
  const unsigned va = pkrtz_u(v0, v1);
  const unsigned vb = pkrtz_u(v2, v3);

  float z = fmaf(xn, 2.80261895f, 4.20392842f);
  z = fminf(fmaxf(z, -8.0f), 16.0f);
  const float d3 = z - 3.60336723f;              // 3*DLT
  const float R3 = __builtin_amdgcn_exp2f(-(d3 * d3));
  const float G  = __builtin_amdgcn_exp2f(z * 2.40224482f);  // 2*DLT
  const float Gi = __builtin_amdgcn_rcpf(G);
  const float R4 = R3 * (G * 9.11881966e-4f);    // e^-7
  const float R5 = R4 * (G * 1.23409804e-4f);    // e^-9
  const float R6 = R5 * (G * 1.67017007e-5f);    // e^-11
  const float R7 = R6 * (G * 2.26032941e-6f);    // e^-13
  const float R2 = R3 * (Gi * 148.413159f);      // e^5
  const float R1 = R2 * (Gi * 20.0855369f);      // e^3
  const float R0 = R1 * (Gi * 2.71828183f);      // e^1

  const int idx = (c < -1 ? -1 : (c > 12 ? 12 : c)) + 1;
  const uint4 sel = lut[idx];
  const unsigned w0 = pkadd_f16(__builtin_amdgcn_perm(vb, va, sel.x), pkrtz_u(R0, R1));
  const unsigned w1 = pkadd_f16(__builtin_amdgcn_perm(vb, va, sel.y), pkrtz_u(R2, R3));
  const unsigned w2 = pkadd_f16(__builtin_amdgcn_perm(vb, va, sel.z), pkrtz_u(R4, R5));
  const unsigned w3 = pkadd_f16(__builtin_amdgcn_perm(vb, va, sel.w), pkrtz_u(R6, R7));
  const uint4 v4 = {w0, w1, w2, w3};
  *(uint4*)dst = v4;  // ds_write_b128
}

// ---------------- fused phase-split f16 MFMA GEMM ------------------------
// LDS slot (r, c) holds global chunk c ^ (r & 7)  (XOR bank swizzle)
#define GLL(g, l)                                               \
  __builtin_amdgcn_global_load_lds(                             \
      (const __attribute__((address_space(1))) void*)(g),       \
      (__attribute__((address_space(3))) void*)(l), 16, 0, 0)

__global__ __launch_bounds__(512, 2) void gemm_kernel(
    const short* __restrict__ A0, const short* __restrict__ XN,
    const short* __restrict__ W, float* __restrict__ out) {
  __shared__ short As[2 * 128 * 64];  // 32 KB, A double-buffer
  __shared__ short Bs[3 * 256 * 64];  // 96 KB, B triple-buffer (depth-2 GLL)
  __shared__ uint4 LUT[14];
  const int tid = threadIdx.x;
  const int lane = tid & 63, wave = tid >> 6;

  // perm-selector LUT: entry idx = c+1, c clamped to [-1,12]
  if (tid < 14) {
    const int cc = tid - 1;
    unsigned e[4];
#pragma unroll
    for (int h = 0; h < 4; ++h) {
      const int m = cc - 2 * h, m2 = m - 1;
      const unsigned lo =
          (m >= 0 && m <= 3) ? (unsigned)((2 * m) | ((2 * m + 1) << 8)) : 0x0C0Cu;
      const unsigned hi =
          (m2 >= 0 && m2 <= 3) ? (unsigned)((2 * m2) | ((2 * m2 + 1) << 8)) : 0x0C0Cu;
      e[h] = lo | (hi << 16);
    }
    const uint4 ev = {e[0], e[1], e[2], e[3]};
    LUT[tid] = ev;
  }

  const int f = blockIdx.x;          // pair 2g,2g+1 shares one A m-tile
  const int m0 = (f >> 1) * 128;
  const int n0 = (f & 1) * 256;
  const int wm = wave & 1, wn = wave >> 1;  // per-wave 64x64 output

  const f32x4 zero = {0.0f, 0.0f, 0.0f, 0.0f};
  f32x4 acc[4][4];
#pragma unroll
  for (int i = 0; i < 4; i++)
#pragma unroll
    for (int j = 0; j < 4; j++) acc[i][j] = zero;

  // staging map: thread -> (row r0 = tid>>3 in 0..63, chunk-slot c0 = tid&7)
  const int r0 = tid >> 3;
  const int c0 = tid & 7;
  const int q0 = c0 ^ (r0 & 7);
  const short* gA = A0 + (size_t)(m0 + r0) * D_IN + q0 * 8;
  const short* gB = W + (size_t)(n0 + r0) * KTOT + q0 * 8;
  const unsigned short* gXa =
      (const unsigned short*)XN + (size_t)(m0 + r0) * D_IN + q0;
  const unsigned short* gXb = gXa + (size_t)64 * D_IN;

  short* Acur = As;        short* Anxt = As + 128 * 64;
  short* Bcur = Bs;        short* Bnxt = Bs + 256 * 64;  short* Bstg = Bs + 2 * 256 * 64;

  const int lr = lane & 15;
  const int q = lane >> 4;
  const int x7 = lr & 7;
  const int offP0 = (q ^ x7) * 8;        // kk2=0 chunk offset
  const int offP1 = ((4 + q) ^ x7) * 8;  // kk2=1 chunk offset

  // prologue: A(0)->Acur, B(0)->Bcur (oldest 6), B(1)->Bnxt (kept in flight
  // until iter-0 wait).  vmcnt(4) drains A(0)+B(0); lgkmcnt(0) publishes LUT.
  GLL(gA, Acur + wave * 512);
  GLL(gA + (size_t)64 * D_IN, Acur + 4096 + wave * 512);
#pragma unroll
  for (int rd = 0; rd < 4; rd++)
    GLL(gB + (size_t)(64 * rd) * KTOT, Bcur + wave * 512 + rd * 4096);
#pragma unroll
  for (int rd = 0; rd < 4; rd++)
    GLL(gB + (size_t)(64 * rd) * KTOT + 64, Bnxt + wave * 512 + rd * 4096);
  asm volatile("s_waitcnt vmcnt(4) lgkmcnt(0)" ::: "memory");
  __builtin_amdgcn_s_barrier();
  __builtin_amdgcn_sched_barrier(0);

  // prologue frag reads: kk2=0 of tile 0
  f16x8 af0[4], bf0[4], af1[4], bf1[4];
#pragma unroll
  for (int mi = 0; mi < 4; mi++)
    af0[mi] = *(const f16x8*)&Acur[(wm * 64 + mi * 16 + lr) * 64 + offP0];
#pragma unroll
  for (int nj = 0; nj < 4; nj++)
    bf0[nj] = *(const f16x8*)&Bcur[(wn * 64 + nj * 16 + lr) * 64 + offP0];

  unsigned short ca = 0, cb = 0;   // xn for tile t+1 basis staging
  unsigned short pa = 0, pb = 0;   // xn for tile t+2 (loaded this iter)

  for (int t = 0; t < NT; ++t) {
    // ---- phase 1: read kk2=1 frags of current tile (feed M1 below) ----
#pragma unroll
    for (int mi = 0; mi < 4; mi++)
      af1[mi] = *(const f16x8*)&Acur[(wm * 64 + mi * 16 + lr) * 64 + offP1];
#pragma unroll
    for (int nj = 0; nj < 4; nj++)
      bf1[nj] = *(const f16x8*)&Bcur[(wn * 64 + nj * 16 + lr) * 64 + offP1];

    // staging: A(t+1) [GLL first = oldest], B(t+2), then xn(t+2)
    const int tp1 = t + 1, tp2 = t + 2;
    if (tp1 < 8) {  // relu region: A via GLL (depth-1)
      GLL(gA + tp1 * 64, Anxt + wave * 512);
      GLL(gA + (size_t)64 * D_IN + tp1 * 64, Anxt + 4096 + wave * 512);
    }
    if (tp2 < NT) {  // B depth-2
#pragma unroll
      for (int rd = 0; rd < 4; rd++)
        GLL(gB + (size_t)(64 * rd) * KTOT + tp2 * 64,
            Bstg + wave * 512 + rd * 4096);
    }
    __builtin_amdgcn_sched_barrier(0);  // pin GLL-before-xn issue order
    if (t >= 6 && t < NT - 2) {         // xn(t+2), consumed next iter
      const int dof = tp2 * 8 - 64;
      pa = gXa[dof];
      pb = gXb[dof];
    }
    if (tp1 >= 8 && tp1 < NT) {  // basis region: compute A(t+1) into Anxt
      basis_write(h2f(ca), LUT, Anxt + r0 * 64 + c0 * 8);
      basis_write(h2f(cb), LUT, Anxt + (r0 + 64) * 64 + c0 * 8);
    }

    // M0: kk2=0 MFMA (operands read in previous phase 2 / prologue)
    __builtin_amdgcn_s_setprio(1);
#pragma unroll
    for (int mi = 0; mi < 4; mi++)
#pragma unroll
      for (int nj = 0; nj < 4; nj++)
        acc[mi][nj] = __builtin_amdgcn_mfma_f32_16x16x32_f16(
            af0[mi], bf0[nj], acc[mi][nj], 0, 0, 0);
    __builtin_amdgcn_s_setprio(0);

    if (tp1 < NT) {
      // publish barrier.  Outstanding VMEM newest->oldest:
      //   [xn(t+2) x2][B(t+2) x4][A(t+1) x2 relu][B(t+1) x4 from prev iter]
      // keep {B(t+2), xn}; drain the rest.  lgkmcnt(0) publishes ds_writes.
      if (t < 6) {
        asm volatile("s_waitcnt vmcnt(4) lgkmcnt(0)" ::: "memory");
      } else if (t < NT - 2) {
        asm volatile("s_waitcnt vmcnt(6) lgkmcnt(0)" ::: "memory");
      } else {
        asm volatile("s_waitcnt vmcnt(0) lgkmcnt(0)" ::: "memory");
      }
      __builtin_amdgcn_s_barrier();
      __builtin_amdgcn_sched_barrier(0);

      // ---- phase 2: read kk2=0 frags of NEXT tile (feed next iter's M0).
      // Independent of M1 below -> LDS port overlaps matrix pipe.
#pragma unroll
      for (int mi = 0; mi < 4; mi++)
        af0[mi] = *(const f16x8*)&Anxt[(wm * 64 + mi * 16 + lr) * 64 + offP0];
#pragma unroll
      for (int nj = 0; nj < 4; nj++)
        bf0[nj] = *(const f16x8*)&Bnxt[(wn * 64 + nj * 16 + lr) * 64 + offP0];
    }

    // M1: kk2=1 MFMA (operands from phase 1, drained by pre-barrier lgkm)
    __builtin_amdgcn_s_setprio(1);
#pragma unroll
    for (int mi = 0; mi < 4; mi++)
#pragma unroll
      for (int nj = 0; nj < 4; nj++)
        acc[mi][nj] = __builtin_amdgcn_mfma_f32_16x16x32_f16(
            af1[mi], bf1[nj], acc[mi][nj], 0, 0, 0);
    __builtin_amdgcn_s_setprio(0);

    // rotate buffers / shift xn pipeline
    short* tA = Acur; Acur = Anxt; Anxt = tA;
    short* tB = Bcur; Bcur = Bnxt; Bnxt = Bstg; Bstg = tB;
    ca = pa; cb = pb;
  }

  // C/D layout (m89-verified): col = lane&15, row = (lane>>4)*4 + reg
#pragma unroll
  for (int mi = 0; mi < 4; mi++) {
#pragma unroll
    for (int nj = 0; nj < 4; nj++) {
      const int gcol = n0 + wn * 64 + nj * 16 + lr;
#pragma unroll
      for (int r = 0; r < 4; r++) {
        const int grow = m0 + wm * 64 + mi * 16 + q * 4 + r;
        out[(size_t)grow * D_OUT + gcol] = acc[mi][nj][r];
      }
    }
  }
}

extern "C" void kernel_launch(void* const* d_in, const int* in_sizes, int n_in,
                              void* d_out, int out_size, void* d_ws, size_t ws_size,
                              hipStream_t stream) {
  const float* x     = (const float*)d_in[0];
  const float* gamma = (const float*)d_in[1];
  const float* beta  = (const float*)d_in[2];
  const float* bw    = (const float*)d_in[3];
  const float* sw    = (const float*)d_in[4];
  float* out = (float*)d_out;

  short* W  = (short*)d_ws;                          // 512 * 4608 f16
  short* XN = W + (size_t)D_OUT * KTOT;              // 16384 * 512 f16
  short* A0 = XN + (size_t)ROWS * D_IN;              // 16384 * 512 f16

  prep_kernel<<<ROWS / 4 + D_OUT, 256, 0, stream>>>(x, gamma, beta, bw, sw,
                                                    XN, A0, W);
  gemm_kernel<<<256, 512, 0, stream>>>(A0, XN, W, out);
}